// Round 9
// baseline (162.117 us; speedup 1.0000x reference)
//
#include <hip/hip_runtime.h>
#include <stdint.h>

#define NFFT    1024
#define HOP     160
#define NMELS   160
#define SEG     32000
#define PADW    512
#define XLEN    33024            // SEG + 2*PADW
#define NFRAMES 201
#define NBATCH  256
#define NFREQ   256
#define TOTFR   (NBATCH * NFRAMES)   // 51456 = 402 * 128
#define FBW     12
#define BM      128
#define BN      128
#define BK      32
#define NSTEP   (NFFT / BK)      // 32
#define OUTSZ   (NBATCH * NMELS * NFRAMES)   // 8232960 floats

using bf16x8 = __attribute__((ext_vector_type(8))) __bf16;
using f32x4  = __attribute__((ext_vector_type(4))) float;

static __device__ __forceinline__ uint16_t f2bf(float f) {
    union { float f; uint32_t u; } v; v.f = f;
    return (uint16_t)((v.u + 0x7FFFu + ((v.u >> 16) & 1u)) >> 16);
}

static __device__ __forceinline__ void gload16(const void* g, void* l) {
    __builtin_amdgcn_global_load_lds(
        (const __attribute__((address_space(1))) uint32_t*)(uintptr_t)g,
        (__attribute__((address_space(3))) uint32_t*)(uintptr_t)l,
        16, 0, 0);
}

// ==== fused prep: pad | btf | fb | zero-out, one launch ====
#define PAD_BLKS  4352            // 256 batches x 17
#define BTF_BLKS  256
#define FB_BLK    1
#define ZERO_BLKS 1005            // 1005*256*32 = 8232960 floats exactly
#define PREP_GRID (PAD_BLKS + BTF_BLKS + FB_BLK + ZERO_BLKS)

__global__ void k_prep(const float* __restrict__ wav, const float* __restrict__ win,
                       const float* __restrict__ dre, const float* __restrict__ dimg,
                       const float* __restrict__ mfb,
                       uint16_t* __restrict__ wp, uint16_t* __restrict__ BTf,
                       int* __restrict__ klo, int* __restrict__ kw,
                       float* __restrict__ fbv, float* __restrict__ out) {
    int bid = blockIdx.x, tid = threadIdx.x;
    if (bid < PAD_BLKS) {
        // reflect-pad waveform -> bf16, 8 elems/thread
        int b = bid / 17, ib = bid - b * 17;
        int i0 = (ib * 256 + tid) * 8;
        if (i0 >= XLEN) return;
        uint16_t r[8];
        if (i0 >= PADW && i0 + 8 <= PADW + SEG) {
            const float* s = wav + (size_t)b * SEG + (i0 - PADW);
            float4 v0 = *(const float4*)s;
            float4 v1 = *(const float4*)(s + 4);
            r[0]=f2bf(v0.x); r[1]=f2bf(v0.y); r[2]=f2bf(v0.z); r[3]=f2bf(v0.w);
            r[4]=f2bf(v1.x); r[5]=f2bf(v1.y); r[6]=f2bf(v1.z); r[7]=f2bf(v1.w);
        } else {
            #pragma unroll
            for (int e = 0; e < 8; ++e) {
                int i = i0 + e, j = i - PADW;
                j = (j < 0) ? -j : ((j >= SEG) ? (2 * SEG - 2 - j) : j);
                r[e] = f2bf(wav[(size_t)b * SEG + j]);
            }
        }
        *(uint4*)(wp + (size_t)b * XLEN + i0) = *(const uint4*)r;
    } else if (bid < PAD_BLKS + BTF_BLKS) {
        // BTf fragment-major: flat (((mat*16+ntile)*32+kstep)*64+lane)*8
        int idx8 = (bid - PAD_BLKS) * 256 + tid;
        int lane  = idx8 & 63;
        int kstep = (idx8 >> 6) & 31;
        int ntile = (idx8 >> 11) & 15;
        int mat   = idx8 >> 15;
        int bin = ntile * 16 + (lane & 15);
        int k0  = kstep * 32 + (lane >> 4) * 8;
        const float* src = (mat ? dimg : dre) + (size_t)bin * 1024 + k0;
        const float* w   = win + k0;
        uint16_t r[8];
        #pragma unroll
        for (int j = 0; j < 8; ++j) r[j] = f2bf(src[j] * w[j]);
        *(uint4*)(BTf + (size_t)idx8 * 8) = *(const uint4*)r;
    } else if (bid < PAD_BLKS + BTF_BLKS + FB_BLK) {
        // compact sparse mel filterbank rows
        int m = tid;
        if (m >= NMELS) return;
        int lo = -1, hi = -1;
        for (int f = 0; f < NFREQ; ++f) {
            float v = mfb[m * 513 + f];
            if (v > 0.f) { if (lo < 0) lo = f; hi = f; }
        }
        int w = (lo < 0) ? 0 : (hi - lo + 1);
        if (w > FBW) w = FBW;
        if (lo < 0) lo = 0;
        klo[m] = lo; kw[m] = w;
        for (int j = 0; j < w; ++j) fbv[m * FBW + j] = mfb[m * 513 + lo + j];
    } else {
        // zero entire output (removes k_fb->k_zero ordering; atomics add onto 0)
        int sub = bid - (PAD_BLKS + BTF_BLKS + FB_BLK);
        float4* p = (float4*)out + ((size_t)sub * 256 + tid) * 8;
        #pragma unroll
        for (int j = 0; j < 8; ++j) p[j] = float4{0.f, 0.f, 0.f, 0.f};
    }
}

// ==== main GEMM: 128 frames x 128 bins (R+I), K=1024, 1 block/CU, deep pipeline
// A: LDS triple-buffer 3x8KB (chunk-swizzled, conflict-free), staged t+2 ahead.
// B: global frag-major, PREFETCHED into regs one iter ahead (contiguous 1KB/wave).
// A-frags ds_read one iter ahead. Steady iter:
//   [BPREF(t+1); vmcnt(4); s_barrier; STAGE(t+2); dsread(t+1); MFMA(t)]
// vmcnt ledger at the wait: {B(t):4, STAGE(t+1):1, B(t+1):4} -> vmcnt(4) drains
// B(t)+STAGE(t+1). STAGE post-barrier: overwrite of buf(t-1) is barrier-separated
// from its last reads (drained pre-MFMA(t-1), which precedes every wave's barrier).
__global__ __launch_bounds__(512, 2) void k_main(
    const uint16_t* __restrict__ wp, const uint16_t* __restrict__ BTf,
    const int* __restrict__ klo, const int* __restrict__ kw,
    const float* __restrict__ fbv, float* __restrict__ out)
{
    __shared__ uint4 smem4[66048 / 16];          // 24KB A bufs; 66KB pw overlay
    char* smem = (char*)smem4;

    const int tid  = threadIdx.x;
    const int lane = tid & 63;
    const int wave = tid >> 6;                   // 8 waves: 2(M) x 4(N)
    const int wm = wave >> 2, wn = wave & 3;
    const int l15 = lane & 15, lg = lane >> 4;
    const int gBase = blockIdx.x * BM;
    const int nb    = blockIdx.y;

    // A staging: 1 chunk/thread; row = tid>>2, linear chunk = tid&3
    const int arow   = tid >> 2;
    const int schunk = (tid & 3) ^ ((arow >> 1) & 3);
    const uint16_t* asrc;
    {
        int g = gBase + arow;
        int b = g / NFRAMES, t = g - b * NFRAMES;
        asrc = wp + (size_t)b * XLEN + t * HOP + schunk * 8;
    }
    const uint32_t arel = (uint32_t)tid * 16;

    // B frag-major base (uint16 units): ntile stride 16384, mat stride 262144,
    // kstep stride 512.  ntile = nb*8 + wn*2 + ni.
    const uint16_t* bbase = BTf + (size_t)(nb * 8 + wn * 2) * 16384 + lane * 8;

    auto STAGE = [&](int buf, int ks) {
        gload16(asrc + (size_t)ks * BK, smem + (uint32_t)buf * 8192u + arel);
    };
    const int rchunk = (lg ^ ((l15 >> 1) & 3)) * 16;
    auto LOADA = [&](bf16x8 (&dst)[4], int t1) {
        const char* Ac = smem + (uint32_t)(t1 % 3) * 8192u;
        #pragma unroll
        for (int mi = 0; mi < 4; ++mi)
            dst[mi] = *(const bf16x8*)(Ac + (wm * 64 + mi * 16 + l15) * 64 + rchunk);
    };
    auto BPREF = [&](bf16x8 (&dst)[4], int ks) {
        dst[0] = *(const bf16x8*)(bbase + (size_t)ks * 512);
        dst[1] = *(const bf16x8*)(bbase + 16384 + (size_t)ks * 512);
        dst[2] = *(const bf16x8*)(bbase + 262144 + (size_t)ks * 512);
        dst[3] = *(const bf16x8*)(bbase + 262144 + 16384 + (size_t)ks * 512);
    };

    f32x4 accR[4][2], accI[4][2];
    #pragma unroll
    for (int mi = 0; mi < 4; ++mi)
        #pragma unroll
        for (int ni = 0; ni < 2; ++ni) {
            accR[mi][ni] = f32x4{0.f, 0.f, 0.f, 0.f};
            accI[mi][ni] = f32x4{0.f, 0.f, 0.f, 0.f};
        }

    bf16x8 aA[4], aB[4], bA[4], bB[4];

    auto MFMA8 = [&](bf16x8 (&a)[4], bf16x8 (&b)[4]) {
        __builtin_amdgcn_s_setprio(1);
        #pragma unroll
        for (int mi = 0; mi < 4; ++mi) {
            accR[mi][0] = __builtin_amdgcn_mfma_f32_16x16x32_bf16(a[mi], b[0], accR[mi][0], 0, 0, 0);
            accR[mi][1] = __builtin_amdgcn_mfma_f32_16x16x32_bf16(a[mi], b[1], accR[mi][1], 0, 0, 0);
            accI[mi][0] = __builtin_amdgcn_mfma_f32_16x16x32_bf16(a[mi], b[2], accI[mi][0], 0, 0, 0);
            accI[mi][1] = __builtin_amdgcn_mfma_f32_16x16x32_bf16(a[mi], b[3], accI[mi][1], 0, 0, 0);
        }
        __builtin_amdgcn_s_setprio(0);
    };

    auto STEP = [&](int t, bf16x8 (&ca)[4], bf16x8 (&na)[4],
                    bf16x8 (&cb)[4], bf16x8 (&nbv)[4]) {
        if (t + 1 < NSTEP) BPREF(nbv, t + 1);
        if (t + 1 < NSTEP) asm volatile("s_waitcnt vmcnt(4)" ::: "memory");
        else               asm volatile("s_waitcnt vmcnt(0)" ::: "memory");
        __builtin_amdgcn_sched_barrier(0);
        __builtin_amdgcn_s_barrier();
        __builtin_amdgcn_sched_barrier(0);
        if (t + 2 < NSTEP) STAGE((t + 2) % 3, t + 2);
        if (t + 1 < NSTEP) LOADA(na, t + 1);
        __builtin_amdgcn_sched_barrier(0);
        MFMA8(ca, cb);
    };

    // prologue: stage buf0,buf1; prefetch B(0); drain stages; publish; read A(0)
    STAGE(0, 0);
    STAGE(1, 1);
    BPREF(bA, 0);
    asm volatile("s_waitcnt vmcnt(4)" ::: "memory");
    __builtin_amdgcn_sched_barrier(0);
    __builtin_amdgcn_s_barrier();
    __builtin_amdgcn_sched_barrier(0);
    LOADA(aA, 0);

    #pragma unroll
    for (int tt = 0; tt < NSTEP; tt += 2) {
        STEP(tt,     aA, aB, bA, bB);
        STEP(tt + 1, aB, aA, bB, bA);
    }

    __syncthreads();

    // ==== epilogue: power f32 -> LDS [128][129] (+1 pad, conflict-free cols)
    float* pw = (float*)smem;
    #pragma unroll
    for (int mi = 0; mi < 4; ++mi)
        #pragma unroll
        for (int ni = 0; ni < 2; ++ni)
            #pragma unroll
            for (int e = 0; e < 4; ++e) {
                int row = wm * 64 + mi * 16 + lg * 4 + e;
                int col = wn * 32 + ni * 16 + l15;
                float r = accR[mi][ni][e], im = accI[mi][ni][e];
                pw[row * (BN + 1) + col] = r * r + im * im;
            }
    __syncthreads();

    // ==== sparse mel projection + transposed store/atomic out[b][m][t]
    const int nbase = nb * BN;
    const int ti = tid & 127;
    {
        int g = gBase + ti;
        int b = g / NFRAMES, tt = g - b * NFRAMES;
        const float* prow = pw + ti * (BN + 1);
        float* obase = out + (size_t)b * (NMELS * NFRAMES) + tt;
        for (int m = (tid >> 7); m < NMELS; m += 4) {
            int lo = klo[m], w = kw[m];
            int i0 = lo < nbase ? nbase : lo;
            int i1 = (lo + w < nbase + BN) ? (lo + w) : (nbase + BN);
            if (i1 <= i0) continue;
            float acc = 0.f;
            for (int j = i0; j < i1; ++j)
                acc += fbv[m * FBW + (j - lo)] * prow[j - nbase];
            float* dst = obase + m * NFRAMES;
            bool full = (lo >= nbase) && (lo + w <= nbase + BN);
            if (full) *dst = acc;
            else      atomicAdd(dst, acc);
        }
    }
}

extern "C" void kernel_launch(void* const* d_in, const int* in_sizes, int n_in,
                              void* d_out, int out_size, void* d_ws, size_t ws_size,
                              hipStream_t stream) {
    const float* wav  = (const float*)d_in[0];
    const float* win  = (const float*)d_in[1];
    const float* dre  = (const float*)d_in[2];
    const float* dimg = (const float*)d_in[3];
    const float* mfb  = (const float*)d_in[4];
    float* out = (float*)d_out;

    uint8_t* ws = (uint8_t*)d_ws;
    uint16_t* BTf = (uint16_t*)ws;                       // 1 MB (fragment-major)
    uint16_t* wp  = (uint16_t*)(ws + (1u << 20));        // 16.9 MB
    size_t off = (1u << 20) + (size_t)NBATCH * XLEN * 2;
    int*   klo = (int*)(ws + off);
    int*   kw  = (int*)(ws + off + 640);
    float* fbv = (float*)(ws + off + 1280);

    hipLaunchKernelGGL(k_prep, dim3(PREP_GRID), dim3(256), 0, stream,
                       wav, win, dre, dimg, mfb, wp, BTf, klo, kw, fbv, out);
    hipLaunchKernelGGL(k_main, dim3(TOTFR / BM, 2), dim3(512), 0, stream,
                       wp, BTf, klo, kw, fbv, out);
}

// Round 10
// 125.663 us; speedup vs baseline: 1.2901x; 1.2901x over previous
//
#include <hip/hip_runtime.h>
#include <stdint.h>

#define NFFT    1024
#define HOP     160
#define NMELS   160
#define SEG     32000
#define PADW    512
#define XLEN    33024            // SEG + 2*PADW
#define NFRAMES 201
#define NBATCH  256
#define NFREQ   256
#define TOTFR   (NBATCH * NFRAMES)   // 51456 = 402 * 128
#define FBW     12
#define BM      128
#define BN      128
#define BK      32
#define NSTEP   (NFFT / BK)      // 32
#define OUTSZ   (NBATCH * NMELS * NFRAMES)   // 8232960 floats

using bf16x8 = __attribute__((ext_vector_type(8))) __bf16;
using f32x4  = __attribute__((ext_vector_type(4))) float;

static __device__ __forceinline__ uint16_t f2bf(float f) {
    union { float f; uint32_t u; } v; v.f = f;
    return (uint16_t)((v.u + 0x7FFFu + ((v.u >> 16) & 1u)) >> 16);
}

static __device__ __forceinline__ void gload16(const void* g, void* l) {
    __builtin_amdgcn_global_load_lds(
        (const __attribute__((address_space(1))) uint32_t*)(uintptr_t)g,
        (__attribute__((address_space(3))) uint32_t*)(uintptr_t)l,
        16, 0, 0);
}

// ==== fused prep: pad | btf | fb | zero-out, one launch ====
#define PAD_BLKS  4352            // 256 batches x 17
#define BTF_BLKS  256
#define FB_BLK    1
#define ZERO_BLKS 1005            // 1005*256*32 = 8232960 floats exactly
#define PREP_GRID (PAD_BLKS + BTF_BLKS + FB_BLK + ZERO_BLKS)

__global__ void k_prep(const float* __restrict__ wav, const float* __restrict__ win,
                       const float* __restrict__ dre, const float* __restrict__ dimg,
                       const float* __restrict__ mfb,
                       uint16_t* __restrict__ wp, uint16_t* __restrict__ BTf,
                       int* __restrict__ klo, int* __restrict__ kw,
                       float* __restrict__ fbv, float* __restrict__ out) {
    int bid = blockIdx.x, tid = threadIdx.x;
    if (bid < PAD_BLKS) {
        int b = bid / 17, ib = bid - b * 17;
        int i0 = (ib * 256 + tid) * 8;
        if (i0 >= XLEN) return;
        uint16_t r[8];
        if (i0 >= PADW && i0 + 8 <= PADW + SEG) {
            const float* s = wav + (size_t)b * SEG + (i0 - PADW);
            float4 v0 = *(const float4*)s;
            float4 v1 = *(const float4*)(s + 4);
            r[0]=f2bf(v0.x); r[1]=f2bf(v0.y); r[2]=f2bf(v0.z); r[3]=f2bf(v0.w);
            r[4]=f2bf(v1.x); r[5]=f2bf(v1.y); r[6]=f2bf(v1.z); r[7]=f2bf(v1.w);
        } else {
            #pragma unroll
            for (int e = 0; e < 8; ++e) {
                int i = i0 + e, j = i - PADW;
                j = (j < 0) ? -j : ((j >= SEG) ? (2 * SEG - 2 - j) : j);
                r[e] = f2bf(wav[(size_t)b * SEG + j]);
            }
        }
        *(uint4*)(wp + (size_t)b * XLEN + i0) = *(const uint4*)r;
    } else if (bid < PAD_BLKS + BTF_BLKS) {
        // BTf fragment-major: flat (((mat*16+ntile)*32+kstep)*64+lane)*8
        int idx8 = (bid - PAD_BLKS) * 256 + tid;
        int lane  = idx8 & 63;
        int kstep = (idx8 >> 6) & 31;
        int ntile = (idx8 >> 11) & 15;
        int mat   = idx8 >> 15;
        int bin = ntile * 16 + (lane & 15);
        int k0  = kstep * 32 + (lane >> 4) * 8;
        const float* src = (mat ? dimg : dre) + (size_t)bin * 1024 + k0;
        const float* w   = win + k0;
        uint16_t r[8];
        #pragma unroll
        for (int j = 0; j < 8; ++j) r[j] = f2bf(src[j] * w[j]);
        *(uint4*)(BTf + (size_t)idx8 * 8) = *(const uint4*)r;
    } else if (bid < PAD_BLKS + BTF_BLKS + FB_BLK) {
        int m = tid;
        if (m >= NMELS) return;
        int lo = -1, hi = -1;
        for (int f = 0; f < NFREQ; ++f) {
            float v = mfb[m * 513 + f];
            if (v > 0.f) { if (lo < 0) lo = f; hi = f; }
        }
        int w = (lo < 0) ? 0 : (hi - lo + 1);
        if (w > FBW) w = FBW;
        if (lo < 0) lo = 0;
        klo[m] = lo; kw[m] = w;
        for (int j = 0; j < w; ++j) fbv[m * FBW + j] = mfb[m * 513 + lo + j];
    } else {
        int sub = bid - (PAD_BLKS + BTF_BLKS + FB_BLK);
        float4* p = (float4*)out + ((size_t)sub * 256 + tid) * 8;
        #pragma unroll
        for (int j = 0; j < 8; ++j) p[j] = float4{0.f, 0.f, 0.f, 0.f};
    }
}

// ==== main GEMM: 128 frames x 128 bins (R+I), K=1024, 2 blocks/CU
// A: LDS triple-buffer 3x8KB (chunk-swizzled), staged t+2 ahead.
// B: global frag-major, loaded in-iter BUT issued BEFORE STAGE so the
//    compiler's pre-MFMA B-wait is vmcnt(1): drains B(t) AND stage(t+1)
//    (issued one iter ago -> latency hidden), keeps stage(t+2) in flight.
//    This replaces R8's accidental vmcnt(0)-every-iter (the 98us serializer).
// Barrier invariant: stage(t+1) drained by every wave's own pre-MFMA wait,
// which precedes its barrier arrival => buf(t+1) visible after barrier.
__global__ __launch_bounds__(512, 4) void k_main(
    const uint16_t* __restrict__ wp, const uint16_t* __restrict__ BTf,
    const int* __restrict__ klo, const int* __restrict__ kw,
    const float* __restrict__ fbv, float* __restrict__ out)
{
    __shared__ uint4 smem4[66048 / 16];          // 24KB A bufs; 66KB pw overlay
    char* smem = (char*)smem4;

    const int tid  = threadIdx.x;
    const int lane = tid & 63;
    const int wave = tid >> 6;                   // 8 waves: 2(M) x 4(N)
    const int wm = wave >> 2, wn = wave & 3;
    const int l15 = lane & 15, lg = lane >> 4;
    const int gBase = blockIdx.x * BM;
    const int nb    = blockIdx.y;

    // A staging: 1 chunk/thread; row = tid>>2, linear chunk = tid&3
    const int arow   = tid >> 2;
    const int schunk = (tid & 3) ^ ((arow >> 1) & 3);
    const uint16_t* asrc;
    {
        int g = gBase + arow;
        int b = g / NFRAMES, t = g - b * NFRAMES;
        asrc = wp + (size_t)b * XLEN + t * HOP + schunk * 8;
    }
    const uint32_t arel = (uint32_t)tid * 16;

    // B frag-major base (uint16 units): ntile stride 16384, mat stride 262144,
    // kstep stride 512.  ntile = nb*8 + wn*2 + ni.
    const uint16_t* bbase = BTf + (size_t)(nb * 8 + wn * 2) * 16384 + lane * 8;

    auto STAGE = [&](int buf, int ks) {
        gload16(asrc + (size_t)ks * BK, smem + (uint32_t)buf * 8192u + arel);
    };
    const int rchunk = (lg ^ ((l15 >> 1) & 3)) * 16;

    f32x4 accR[4][2], accI[4][2];
    #pragma unroll
    for (int mi = 0; mi < 4; ++mi)
        #pragma unroll
        for (int ni = 0; ni < 2; ++ni) {
            accR[mi][ni] = f32x4{0.f, 0.f, 0.f, 0.f};
            accI[mi][ni] = f32x4{0.f, 0.f, 0.f, 0.f};
        }

    // prologue: stage buf0, buf1; drain own buf0 staging; publish
    STAGE(0, 0);
    STAGE(1, 1);
    asm volatile("s_waitcnt vmcnt(1)" ::: "memory");
    __builtin_amdgcn_s_barrier();
    __builtin_amdgcn_sched_barrier(0);

    #pragma unroll
    for (int t = 0; t < NSTEP; ++t) {
        // 1) B loads FIRST (oldest of this iter's VMEM ops)
        bf16x8 br[2], bi[2];
        #pragma unroll
        for (int ni = 0; ni < 2; ++ni) {
            br[ni] = *(const bf16x8*)(bbase + (size_t)ni * 16384 + (size_t)t * 512);
            bi[ni] = *(const bf16x8*)(bbase + 262144 + (size_t)ni * 16384 + (size_t)t * 512);
        }
        __builtin_amdgcn_sched_barrier(0);
        // 2) stage A for t+2 (newest VMEM op -> survives the B-wait)
        if (t + 2 < NSTEP) STAGE((t + 2) % 3, t + 2);
        __builtin_amdgcn_sched_barrier(0);
        // 3) A frags from LDS buf t%3
        const char* Ac = smem + (uint32_t)(t % 3) * 8192u;
        bf16x8 a[4];
        #pragma unroll
        for (int mi = 0; mi < 4; ++mi)
            a[mi] = *(const bf16x8*)(Ac + (wm * 64 + mi * 16 + l15) * 64 + rchunk);
        // 4) MFMA (compiler inserts vmcnt(1) for B -> also drains stage(t+1);
        //    lgkmcnt for A)
        __builtin_amdgcn_s_setprio(1);
        #pragma unroll
        for (int mi = 0; mi < 4; ++mi) {
            accR[mi][0] = __builtin_amdgcn_mfma_f32_16x16x32_bf16(a[mi], br[0], accR[mi][0], 0, 0, 0);
            accR[mi][1] = __builtin_amdgcn_mfma_f32_16x16x32_bf16(a[mi], br[1], accR[mi][1], 0, 0, 0);
            accI[mi][0] = __builtin_amdgcn_mfma_f32_16x16x32_bf16(a[mi], bi[0], accI[mi][0], 0, 0, 0);
            accI[mi][1] = __builtin_amdgcn_mfma_f32_16x16x32_bf16(a[mi], bi[1], accI[mi][1], 0, 0, 0);
        }
        __builtin_amdgcn_s_setprio(0);
        // 5) barrier: stage(t+1) already drained by this wave's B-wait above
        if (t + 1 < NSTEP) {
            __builtin_amdgcn_sched_barrier(0);
            __builtin_amdgcn_s_barrier();
            __builtin_amdgcn_sched_barrier(0);
        }
    }

    __syncthreads();

    // ==== epilogue: power f32 -> LDS [128][129] (+1 pad, conflict-free cols)
    float* pw = (float*)smem;
    #pragma unroll
    for (int mi = 0; mi < 4; ++mi)
        #pragma unroll
        for (int ni = 0; ni < 2; ++ni)
            #pragma unroll
            for (int e = 0; e < 4; ++e) {
                int row = wm * 64 + mi * 16 + lg * 4 + e;
                int col = wn * 32 + ni * 16 + l15;
                float r = accR[mi][ni][e], im = accI[mi][ni][e];
                pw[row * (BN + 1) + col] = r * r + im * im;
            }
    __syncthreads();

    // ==== sparse mel projection + transposed store/atomic out[b][m][t]
    const int nbase = nb * BN;
    const int ti = tid & 127;
    {
        int g = gBase + ti;
        int b = g / NFRAMES, tt = g - b * NFRAMES;
        const float* prow = pw + ti * (BN + 1);
        float* obase = out + (size_t)b * (NMELS * NFRAMES) + tt;
        for (int m = (tid >> 7); m < NMELS; m += 4) {
            int lo = klo[m], w = kw[m];
            int i0 = lo < nbase ? nbase : lo;
            int i1 = (lo + w < nbase + BN) ? (lo + w) : (nbase + BN);
            if (i1 <= i0) continue;
            float acc = 0.f;
            for (int j = i0; j < i1; ++j)
                acc += fbv[m * FBW + (j - lo)] * prow[j - nbase];
            float* dst = obase + m * NFRAMES;
            bool full = (lo >= nbase) && (lo + w <= nbase + BN);
            if (full) *dst = acc;
            else      atomicAdd(dst, acc);
        }
    }
}

extern "C" void kernel_launch(void* const* d_in, const int* in_sizes, int n_in,
                              void* d_out, int out_size, void* d_ws, size_t ws_size,
                              hipStream_t stream) {
    const float* wav  = (const float*)d_in[0];
    const float* win  = (const float*)d_in[1];
    const float* dre  = (const float*)d_in[2];
    const float* dimg = (const float*)d_in[3];
    const float* mfb  = (const float*)d_in[4];
    float* out = (float*)d_out;

    uint8_t* ws = (uint8_t*)d_ws;
    uint16_t* BTf = (uint16_t*)ws;                       // 1 MB (fragment-major)
    uint16_t* wp  = (uint16_t*)(ws + (1u << 20));        // 16.9 MB
    size_t off = (1u << 20) + (size_t)NBATCH * XLEN * 2;
    int*   klo = (int*)(ws + off);
    int*   kw  = (int*)(ws + off + 640);
    float* fbv = (float*)(ws + off + 1280);

    hipLaunchKernelGGL(k_prep, dim3(PREP_GRID), dim3(256), 0, stream,
                       wav, win, dre, dimg, mfb, wp, BTf, klo, kw, fbv, out);
    hipLaunchKernelGGL(k_main, dim3(TOTFR / BM, 2), dim3(512), 0, stream,
                       wp, BTf, klo, kw, fbv, out);
}